// Round 4
// baseline (25.183 us; speedup 1.0000x reference)
//
#include <hip/hip_runtime.h>
#include <math.h>

#define SR_I 16000
#define FRAMES 500
#define UP 64
#define AUDIO (FRAMES * UP)
#define POLY 8
#define HARM 64
#define NYQ 8000.0f

// largest n with (float)n * f < NYQ under exact f32 semantics
__device__ __forceinline__ int nyq_limit(float f) {
    int m = (int)(NYQ / f);
    while ((float)(m + 1) * f < NYQ) ++m;
    while (m > 0 && (float)m * f >= NYQ) --m;
    return m;
}

// -------------------------------------------------------------------------
// Single fused kernel: one block per (b, frame t); 8 waves; wave p = voice p.
// Lane k owns output sample j = t*64 + k.
//
// Frame-level phase prefix (closed form, t>=1):
//   P[t] = (64*S_t + 8*(x[t]-x[t-1])) / SR,   S_t = sum_{j<t} x[j]
// derived from telescoping the per-frame sums of upsample(f0) with
// scale=64, align_corners=False (interior frame sum = 8*x[t-1]+48*x[t]+8*x[t+1],
// boundaries 56/8 and 8/56).  S_t is computed per-wave with a coalesced
// f64 reduction — no cross-block scan, no second kernel.
//
// In-frame: 64-lane f64 shuffle scan of the per-sample increments, then the
// harmonic loop runs in f32 on phi = frac(Phi): one ds_read_b128 (2-way
// broadcast) + ~10 VALU + v_sin per harmonic, 4x unrolled.
// -------------------------------------------------------------------------
__global__ __launch_bounds__(512) void k_fused(const float* __restrict__ f0,
                                               const float* __restrict__ cc,
                                               const float* __restrict__ vv,
                                               const float* __restrict__ rp,
                                               float* __restrict__ out) {
    __shared__ float4 quads[POLY][2][HARM];   // 16 KiB
    __shared__ float part[POLY][UP];          // 2 KiB

    const int blk = blockIdx.x;           // 0 .. 2*FRAMES-1
    const int b = blk / FRAMES;
    const int t = blk - b * FRAMES;
    const int tid = threadIdx.x;
    const int p = tid >> 6;               // wave index = voice
    const int k = tid & 63;

    // linear-interp coords for sample j = t*64 + k (exact in f32)
    float srcf = (float)t + ((float)k - 31.5f) * (1.0f / 64.0f);
    srcf = fmaxf(srcf, 0.0f);
    const int i0 = (int)srcf;
    const int i1 = min(i0 + 1, FRAMES - 1);
    const float w = srcf - (float)i0;
    const float w1 = 1.0f - w;

    const int tm = max(t - 1, 0);
    const int tp = min(t + 1, FRAMES - 1);

    const int bpi = b * POLY + p;
    const float* f0p = f0 + bpi * FRAMES;
    const float* vp  = vv + bpi * FRAMES;
    const float* cp  = cc + (size_t)bpi * HARM * FRAMES;

    // stage per-voice quads: lane k holds harmonic k
    const float chm = cp[k * FRAMES + tm];
    const float chc = cp[k * FRAMES + t];
    const float chp = cp[k * FRAMES + tp];
    const float rpl = rp[bpi * HARM + k];
    quads[p][0][k] = make_float4(chm, chc, rpl, 0.0f);   // lanes 0..31
    quads[p][1][k] = make_float4(chc, chp, rpl, 0.0f);   // lanes 32..63

    // ---- frame-level prefix via closed form (per-wave f64 reduction) ----
    double ssum = 0.0;
    for (int j = k; j < t; j += 64) ssum += (double)f0p[j];
    #pragma unroll
    for (int off = 32; off; off >>= 1)
        ssum += __shfl_xor(ssum, off, 64);
    double Pfr = 0.0;
    if (t > 0) {
        const double xt  = (double)f0p[t];
        const double xtm = (double)f0p[t - 1];
        Pfr = (64.0 * ssum + 8.0 * (xt - xtm)) * (1.0 / (double)SR_I);
    }

    const float f00 = f0p[i0];
    const float f01 = f0p[i1];
    const float vup04 = 0.04f * (w1 * vp[i0] + w * vp[i1]);
    const float W0 = w1 * vup04;
    const float W1 = w * vup04;

    // exact per-lane anti-alias limits (mask n<=N passes)
    const int N0 = nyq_limit(f00);
    const int N1 = nyq_limit(f01);

    // in-frame 64-lane inclusive scan of per-sample increments (f64)
    double s = ((double)w1 * (double)f00 + (double)w * (double)f01)
               * (1.0 / (double)SR_I);
    #pragma unroll
    for (int off = 1; off < 64; off <<= 1) {
        double o = __shfl_up(s, off, 64);
        if (k >= off) s += o;
    }
    const double Phi = Pfr + s;
    const float phi = (float)(Phi - floor(Phi));   // exact frac, then f32

    // wave-uniform harmonic cap, rounded up to 4 (extras are masked to zero)
    int nmax = max(N0, N1);
    #pragma unroll
    for (int off = 32; off; off >>= 1)
        nmax = max(nmax, __shfl_xor(nmax, off, 64));
    int hmax = min(nmax, HARM);
    hmax = (hmax + 3) & ~3;

    const float4* qb = &quads[p][k < 32 ? 0 : 1][0];

    float acc0 = 0.0f, acc1 = 0.0f, acc2 = 0.0f, acc3 = 0.0f;
    float nf0 = 1.0f, nf1 = 2.0f, nf2 = 3.0f, nf3 = 4.0f;

    for (int n0 = 1; n0 <= hmax; n0 += 4) {
        const float4 qa = qb[n0 - 1];
        const float4 qc = qb[n0 + 0];
        const float4 qd = qb[n0 + 1];
        const float4 qe = qb[n0 + 2];

        {
            float c0 = (n0 <= N0) ? qa.x : 0.0f;
            float c1 = (n0 <= N1) ? qa.y : 0.0f;
            float cup = fmaf(W1, c1, W0 * c0);
            float ph = fmaf(nf0, phi, qa.z);
            acc0 = fmaf(cup, __builtin_amdgcn_sinf(__builtin_amdgcn_fractf(ph)), acc0);
        }
        {
            float c0 = (n0 + 1 <= N0) ? qc.x : 0.0f;
            float c1 = (n0 + 1 <= N1) ? qc.y : 0.0f;
            float cup = fmaf(W1, c1, W0 * c0);
            float ph = fmaf(nf1, phi, qc.z);
            acc1 = fmaf(cup, __builtin_amdgcn_sinf(__builtin_amdgcn_fractf(ph)), acc1);
        }
        {
            float c0 = (n0 + 2 <= N0) ? qd.x : 0.0f;
            float c1 = (n0 + 2 <= N1) ? qd.y : 0.0f;
            float cup = fmaf(W1, c1, W0 * c0);
            float ph = fmaf(nf2, phi, qd.z);
            acc2 = fmaf(cup, __builtin_amdgcn_sinf(__builtin_amdgcn_fractf(ph)), acc2);
        }
        {
            float c0 = (n0 + 3 <= N0) ? qe.x : 0.0f;
            float c1 = (n0 + 3 <= N1) ? qe.y : 0.0f;
            float cup = fmaf(W1, c1, W0 * c0);
            float ph = fmaf(nf3, phi, qe.z);
            acc3 = fmaf(cup, __builtin_amdgcn_sinf(__builtin_amdgcn_fractf(ph)), acc3);
        }
        nf0 += 4.0f; nf1 += 4.0f; nf2 += 4.0f; nf3 += 4.0f;
    }

    part[p][k] = (acc0 + acc1) + (acc2 + acc3);
    __syncthreads();
    if (tid < 64) {
        float sum = 0.0f;
        #pragma unroll
        for (int q = 0; q < POLY; ++q) sum += part[q][tid];
        out[(size_t)b * AUDIO + t * UP + tid] = sum;
    }
}

extern "C" void kernel_launch(void* const* d_in, const int* in_sizes, int n_in,
                              void* d_out, int out_size, void* d_ws, size_t ws_size,
                              hipStream_t stream) {
    const float* f0 = (const float*)d_in[0];   // (2,8,500)
    const float* c  = (const float*)d_in[1];   // (2,8,64,500)
    const float* v  = (const float*)d_in[2];   // (2,8,500)
    // d_in[3] = a (loudness) — unused by the output
    const float* rp = (const float*)d_in[4];   // (2,512,1)
    float* out = (float*)d_out;                // (2,32000)

    k_fused<<<2 * FRAMES, 512, 0, stream>>>(f0, c, v, rp, out);
}

// Round 5
// 16.709 us; speedup vs baseline: 1.5072x; 1.5072x over previous
//
#include <hip/hip_runtime.h>
#include <math.h>

#define SR_I 16000
#define FRAMES 500
#define UP 64
#define AUDIO (FRAMES * UP)
#define POLY 8
#define HARM 64
#define NYQ 8000.0f

// -------------------------------------------------------------------------
// Single fused kernel: one block per (b, frame t); 8 waves; wave p = voice p.
// Lane k owns output sample j = t*64 + k.
//
// Frame-level phase prefix (closed form, exact telescoping of the per-frame
// sums of upsample(f0), scale=64, align_corners=False):
//   P[t] = (64*S_t + 8*(x[t]-x[t-1])) / SR,  S_t = sum_{j<t} x[j]   (P[0]=0,
//   falls out automatically since the t=0 clamp gives x[tm]=x[t]).
//
// In-frame inclusive scan (closed form, increments are linear in lane k):
//   lanes 0..31 : w=(k+32.5)/64 over (A=x[t-1] -> B=x[t])
//     S(k) = [(k+1)A + (B-A)*(k(k+1)/2 + 32.5(k+1))/64]/SR
//   lanes 32..63: q=k-32, w=(q+0.5)/64 over (B -> C=x[t+1])
//     S(k) = (8A+24B)/SR + [(q+1)B + (C-B)*(q+1)^2/128]/SR
//   Boundary clamps (t=0, t=499) collapse to A=B / C=B and stay exact.
//
// Anti-alias mask ((float)n * x_frame < 8000, per reference: applied to c
// per frame BEFORE upsampling) is baked into the LDS quads at staging, so
// the harmonic loop is: ds_read_b128 + fma + fma + fract + v_sin + fma.
// -------------------------------------------------------------------------
__global__ __launch_bounds__(512) void k_fused(const float* __restrict__ f0,
                                               const float* __restrict__ cc,
                                               const float* __restrict__ vv,
                                               const float* __restrict__ rp,
                                               float* __restrict__ out) {
    __shared__ float4 quads[POLY][2][HARM];   // 16 KiB
    __shared__ float part[POLY][UP];          // 2 KiB

    const int blk = blockIdx.x;           // 0 .. 2*FRAMES-1
    const int b = blk / FRAMES;
    const int t = blk - b * FRAMES;
    const int tid = threadIdx.x;
    const int p = tid >> 6;               // wave index = voice
    const int k = tid & 63;
    const bool lowhalf = (k < 32);

    const int tm = max(t - 1, 0);
    const int tp = min(t + 1, FRAMES - 1);

    const int bpi = b * POLY + p;
    const float* f0p = f0 + bpi * FRAMES;
    const float* vp  = vv + bpi * FRAMES;
    const float* cp  = cc + (size_t)bpi * HARM * FRAMES;

    // wave-uniform frame values
    const float A = f0p[tm];
    const float B = f0p[t];
    const float C = f0p[tp];
    const float vA = vp[tm];
    const float vB = vp[t];
    const float vC = vp[tp];

    // ---- stage pre-masked quads: lane k holds harmonic k (n = k+1) ----
    const float nf = (float)(k + 1);
    const bool mA = (nf * A < NYQ);
    const bool mB = (nf * B < NYQ);
    const bool mC = (nf * C < NYQ);
    const float cA = mA ? cp[k * FRAMES + tm] : 0.0f;
    const float cB = mB ? cp[k * FRAMES + t]  : 0.0f;
    const float cC = mC ? cp[k * FRAMES + tp] : 0.0f;
    const float rpl = rp[bpi * HARM + k];
    quads[p][0][k] = make_float4(cA, cB, rpl, 0.0f);   // lanes 0..31: (i0,i1)=(tm,t)
    quads[p][1][k] = make_float4(cB, cC, rpl, 0.0f);   // lanes 32..63: (t,tp)

    // wave-uniform harmonic cap (mask monotone in n)
    const unsigned long long bal = __ballot(mA || mB || mC);
    int hmax = (int)__popcll(bal);
    hmax = (hmax + 3) & ~3;

    // ---- frame prefix P[t] (f64): coalesced partial sums + xor reduce ----
    double ssum = 0.0;
    for (int j = k; j < t; j += 64) ssum += (double)f0p[j];
    #pragma unroll
    for (int off = 32; off; off >>= 1)
        ssum += __shfl_xor(ssum, off, 64);
    const double dA = (double)A, dB = (double)B, dC = (double)C;
    const double Pfr = (64.0 * ssum + 8.0 * (dB - dA)) * (1.0 / (double)SR_I);

    // ---- in-frame inclusive scan, closed form ----
    double S;
    if (lowhalf) {
        const double kk = (double)k;
        S = ((kk + 1.0) * dA
             + (dB - dA) * (kk * (kk + 1.0) * 0.5 + 32.5 * (kk + 1.0)) * (1.0 / 64.0))
            * (1.0 / (double)SR_I);
    } else {
        const double qq = (double)(k - 32);
        S = (8.0 * dA + 24.0 * dB) * (1.0 / (double)SR_I)
            + ((qq + 1.0) * dB + (dC - dB) * (qq + 1.0) * (qq + 1.0) * (1.0 / 128.0))
              * (1.0 / (double)SR_I);
    }
    const double Phi = Pfr + S;
    const float phi = (float)(Phi - floor(Phi));   // exact frac, then f32

    // per-lane interpolation weights and v envelope
    const float w = (lowhalf ? ((float)k + 32.5f) : ((float)k - 31.5f)) * (1.0f / 64.0f);
    const float w1 = 1.0f - w;
    const float v0 = lowhalf ? vA : vB;
    const float v1 = lowhalf ? vB : vC;
    const float vup04 = 0.04f * (w1 * v0 + w * v1);
    const float W0 = w1 * vup04;
    const float W1 = w * vup04;

    const float4* qb = &quads[p][lowhalf ? 0 : 1][0];

    float acc0 = 0.0f, acc1 = 0.0f, acc2 = 0.0f, acc3 = 0.0f;
    float nf0 = 1.0f, nf1 = 2.0f, nf2 = 3.0f, nf3 = 4.0f;

    for (int n0 = 1; n0 <= hmax; n0 += 4) {
        const float4 qa = qb[n0 - 1];
        const float4 qc = qb[n0 + 0];
        const float4 qd = qb[n0 + 1];
        const float4 qe = qb[n0 + 2];

        {
            const float cup = fmaf(W1, qa.y, W0 * qa.x);
            const float ph  = fmaf(nf0, phi, qa.z);
            acc0 = fmaf(cup, __builtin_amdgcn_sinf(__builtin_amdgcn_fractf(ph)), acc0);
        }
        {
            const float cup = fmaf(W1, qc.y, W0 * qc.x);
            const float ph  = fmaf(nf1, phi, qc.z);
            acc1 = fmaf(cup, __builtin_amdgcn_sinf(__builtin_amdgcn_fractf(ph)), acc1);
        }
        {
            const float cup = fmaf(W1, qd.y, W0 * qd.x);
            const float ph  = fmaf(nf2, phi, qd.z);
            acc2 = fmaf(cup, __builtin_amdgcn_sinf(__builtin_amdgcn_fractf(ph)), acc2);
        }
        {
            const float cup = fmaf(W1, qe.y, W0 * qe.x);
            const float ph  = fmaf(nf3, phi, qe.z);
            acc3 = fmaf(cup, __builtin_amdgcn_sinf(__builtin_amdgcn_fractf(ph)), acc3);
        }
        nf0 += 4.0f; nf1 += 4.0f; nf2 += 4.0f; nf3 += 4.0f;
    }

    part[p][k] = (acc0 + acc1) + (acc2 + acc3);
    __syncthreads();
    if (tid < 64) {
        float sum = 0.0f;
        #pragma unroll
        for (int q = 0; q < POLY; ++q) sum += part[q][tid];
        out[(size_t)b * AUDIO + t * UP + tid] = sum;
    }
}

extern "C" void kernel_launch(void* const* d_in, const int* in_sizes, int n_in,
                              void* d_out, int out_size, void* d_ws, size_t ws_size,
                              hipStream_t stream) {
    const float* f0 = (const float*)d_in[0];   // (2,8,500)
    const float* c  = (const float*)d_in[1];   // (2,8,64,500)
    const float* v  = (const float*)d_in[2];   // (2,8,500)
    // d_in[3] = a (loudness) — unused by the output
    const float* rp = (const float*)d_in[4];   // (2,512,1)
    float* out = (float*)d_out;                // (2,32000)

    k_fused<<<2 * FRAMES, 512, 0, stream>>>(f0, c, v, rp, out);
}